// Round 9
// baseline (257.848 us; speedup 1.0000x reference)
//
#include <hip/hip_runtime.h>
#include <math.h>

#define NH_ 8
#define L_ 3
#define P_ 8
#define HD_ 32
#define C_ 256
#define B_ 4
#define NQ 2048
#define S_ 13125

typedef unsigned short ushort;
typedef unsigned int uint;

using short8 = __attribute__((ext_vector_type(8))) short;
using f32x4  = __attribute__((ext_vector_type(4))) float;

typedef unsigned int u32_as1 __attribute__((address_space(1)));
typedef unsigned int u32_as3 __attribute__((address_space(3)));

__device__ __forceinline__ void gload16(const ushort* g, ushort* l) {
    // async global->LDS, 16B per lane; LDS dest = wave-uniform base + lane*16
    __builtin_amdgcn_global_load_lds((const u32_as1*)g, (u32_as3*)l, 16, 0, 0);
}

__device__ __forceinline__ ushort f2bf(float f) {
    union { float f; uint i; } v; v.f = f;
    const uint x = v.i;
    return (ushort)((x + 0x7FFFu + ((x >> 16) & 1u)) >> 16);  // RTNE
}
__device__ __forceinline__ float bf2f(ushort u) {
    union { uint i; float f; } v; v.i = ((uint)u) << 16; return v.f;
}
__device__ __forceinline__ uint pk2(float lo, float hi) {
    return (uint)f2bf(lo) | ((uint)f2bf(hi) << 16);
}

// ---------------------------------------------------------------------------
// Tiled bf16 layout for GEMM staging (per logical [R][256] matrix, R pad 128):
//   ushort offset(r,k) = t*32768 + s*4096 + w*1024 + rh*512 + lane*8 + e
//   where t=r>>7, rh=(r>>6)&1, lane=r&63, s=k>>5, w=(k>>3)&3, e=k&7.
// One chunk id = 8 ushorts; chunk c within tile: s=c>>9, w=(c>>7)&3,
// rh=(c>>6)&1, lane=c&63. Staging then reads 1KB contiguous per wave-inst.
// ---------------------------------------------------------------------------
__global__ __launch_bounds__(256) void convert_kernel(
    const float* __restrict__ memory, const float* __restrict__ query,
    const float* __restrict__ W_off, const float* __restrict__ W_attn,
    const float* __restrict__ W_val, const float* __restrict__ W_out,
    ushort* __restrict__ memB, ushort* __restrict__ queryB,
    ushort* __restrict__ WcatT, ushort* __restrict__ W_valT,
    ushort* __restrict__ W_outT)
{
    const uint id = blockIdx.x * 256u + threadIdx.x;
    float v[8];

    if (id < 1687552u) {                       // memB: [z][103 tiles][4096 chunks]
        const uint z = id / 421888u, rem = id % 421888u;
        const uint t = rem >> 12, c = rem & 4095u;
        const uint s = c >> 9, w = (c >> 7) & 3u, rh = (c >> 6) & 1u, ln = c & 63u;
        const uint r = min(t * 128u + rh * 64u + ln, 13124u);
        const uint k = s * 32u + w * 8u;
        const float* src = memory + ((size_t)z * 13125u + r) * 256u + k;
        const float4 a = *(const float4*)src;
        const float4 b = *(const float4*)(src + 4);
        uint4 o; o.x = pk2(a.x, a.y); o.y = pk2(a.z, a.w);
                 o.z = pk2(b.x, b.y); o.w = pk2(b.z, b.w);
        *(uint4*)(memB + (size_t)id * 8) = o;
    } else if (id < 1949696u) {                // queryB: 64 tiles (8192 rows exact)
        const uint local = id - 1687552u;
        const uint t = local >> 12, c = local & 4095u;
        const uint s = c >> 9, w = (c >> 7) & 3u, rh = (c >> 6) & 1u, ln = c & 63u;
        const uint r = t * 128u + rh * 64u + ln;
        const uint k = s * 32u + w * 8u;
        const float* src = query + (size_t)r * 256u + k;
        const float4 a = *(const float4*)src;
        const float4 b = *(const float4*)(src + 4);
        uint4 o; o.x = pk2(a.x, a.y); o.y = pk2(a.z, a.w);
                 o.z = pk2(b.x, b.y); o.w = pk2(b.z, b.w);
        *(uint4*)(queryB + (size_t)local * 8) = o;
    } else if (id < 1957888u) {                // W_valT: 2 tiles (n=256 exact)
        const uint local = id - 1949696u;
        const uint t = local >> 12, c = local & 4095u;
        const uint s = c >> 9, w = (c >> 7) & 3u, rh = (c >> 6) & 1u, ln = c & 63u;
        const uint n = t * 128u + rh * 64u + ln;
        const uint k = s * 32u + w * 8u;
        #pragma unroll
        for (int e = 0; e < 8; ++e) v[e] = W_val[(size_t)(k + e) * 256u + n];
        uint4 o; o.x = pk2(v[0], v[1]); o.y = pk2(v[2], v[3]);
                 o.z = pk2(v[4], v[5]); o.w = pk2(v[6], v[7]);
        *(uint4*)(W_valT + (size_t)local * 8) = o;
    } else if (id < 1978368u) {                // WcatT: 5 tiles (576 cols, pad clamp)
        const uint local = id - 1957888u;
        const uint t = local >> 12, c = local & 4095u;
        const uint s = c >> 9, w = (c >> 7) & 3u, rh = (c >> 6) & 1u, ln = c & 63u;
        const uint n = min(t * 128u + rh * 64u + ln, 575u);
        const uint k = s * 32u + w * 8u;
        #pragma unroll
        for (int e = 0; e < 8; ++e)
            v[e] = (n < 384u) ? W_off[(size_t)(k + e) * 384u + n]
                              : W_attn[(size_t)(k + e) * 192u + (n - 384u)];
        uint4 o; o.x = pk2(v[0], v[1]); o.y = pk2(v[2], v[3]);
                 o.z = pk2(v[4], v[5]); o.w = pk2(v[6], v[7]);
        *(uint4*)(WcatT + (size_t)local * 8) = o;
    } else if (id < 1986560u) {                // W_outT: 2 tiles
        const uint local = id - 1978368u;
        const uint t = local >> 12, c = local & 4095u;
        const uint s = c >> 9, w = (c >> 7) & 3u, rh = (c >> 6) & 1u, ln = c & 63u;
        const uint n = t * 128u + rh * 64u + ln;
        const uint k = s * 32u + w * 8u;
        #pragma unroll
        for (int e = 0; e < 8; ++e) v[e] = W_out[(size_t)(k + e) * 256u + n];
        uint4 o; o.x = pk2(v[0], v[1]); o.y = pk2(v[2], v[3]);
                 o.z = pk2(v[4], v[5]); o.w = pk2(v[6], v[7]);
        *(uint4*)(W_outT + (size_t)local * 8) = o;
    }
}

// ---------------------------------------------------------------------------
// bf16 MFMA GEMM on tiled operands. 128x128 tile, 4 waves (2x2), K-step 32,
// 2-phase LDS dbuf, global_load_lds reads 1KB contiguous per instruction.
// MODE 0: A=memB(batch z), WT=W_valT -> value bf16 [B][NH][S][HD] (+b_val)
// MODE 1: A=queryB,        WT=WcatT  -> projQ f32 [8192][576]
// MODE 2: A=out_preB_t,    WT=W_outT -> d_out f32 [8192][256] (+b_out)
// ---------------------------------------------------------------------------
template <int MODE>
__global__ __launch_bounds__(256) void gemm_mfma(
    const ushort* __restrict__ A, const ushort* __restrict__ WT,
    const float* __restrict__ bias1, const float* __restrict__ bias2,
    void* __restrict__ outp)
{
    const int tid = threadIdx.x;
    const int wid = tid >> 6, lane = tid & 63;
    const int l15 = lane & 15, kcl = lane >> 4;
    const int wr = wid >> 1, wc = wid & 1;

    const ushort* Ab;
    if constexpr (MODE == 0) Ab = A + (size_t)blockIdx.z * 3375104u;  // 103*32768
    else                     Ab = A;

    const int row0 = blockIdx.x * 128, n0 = blockIdx.y * 128;

    __shared__ ushort As[2][4096];   // [kchunk(=wid)][128 rows][8 k]
    __shared__ ushort Bs[2][4096];

    f32x4 acc[4][4] = {};

    auto stage = [&](int buf, int s) {
        const size_t abase = ((size_t)(blockIdx.x * 8 + s)) * 4096 + wid * 1024 + lane * 8;
        const size_t bbase = ((size_t)(blockIdx.y * 8 + s)) * 4096 + wid * 1024 + lane * 8;
        #pragma unroll
        for (int rh = 0; rh < 2; ++rh) {
            gload16(Ab + abase + rh * 512, &As[buf][wid * 1024 + rh * 512]);
            gload16(WT + bbase + rh * 512, &Bs[buf][wid * 1024 + rh * 512]);
        }
    };

    stage(0, 0);
    __syncthreads();

    #pragma unroll
    for (int kt = 0; kt < 8; ++kt) {
        const int cur = kt & 1;
        if (kt < 7) stage(cur ^ 1, kt + 1);

        short8 af[4], bf[4];
        #pragma unroll
        for (int mi = 0; mi < 4; ++mi)
            af[mi] = *(const short8*)&As[cur][kcl * 1024 + (wr * 64 + mi * 16 + l15) * 8];
        #pragma unroll
        for (int ni = 0; ni < 4; ++ni)
            bf[ni] = *(const short8*)&Bs[cur][kcl * 1024 + (wc * 64 + ni * 16 + l15) * 8];
        #pragma unroll
        for (int mi = 0; mi < 4; ++mi)
            #pragma unroll
            for (int ni = 0; ni < 4; ++ni)
                acc[mi][ni] = __builtin_amdgcn_mfma_f32_16x16x32_bf16(
                    af[mi], bf[ni], acc[mi][ni], 0, 0, 0);
        __syncthreads();
    }

    // epilogue: C/D layout col = lane&15, row = (lane>>4)*4 + reg
    #pragma unroll
    for (int ni = 0; ni < 4; ++ni) {
        const int n = n0 + wc * 64 + ni * 16 + l15;
        if constexpr (MODE == 0) {
            ushort* value = (ushort*)outp;
            const int h = n >> 5, d = n & 31;
            const float bv = bias1[n];
            #pragma unroll
            for (int mi = 0; mi < 4; ++mi)
                #pragma unroll
                for (int r = 0; r < 4; ++r) {
                    const int s = row0 + wr * 64 + mi * 16 + kcl * 4 + r;
                    if (s < S_)
                        value[(((size_t)blockIdx.z * NH_ + h) * S_ + s) * HD_ + d] =
                            f2bf(acc[mi][ni][r] + bv);
                }
        } else if constexpr (MODE == 1) {
            if (n < 576) {
                float* o = (float*)outp;
                const float bv = (n < 384) ? bias1[n] : bias2[n - 384];
                #pragma unroll
                for (int mi = 0; mi < 4; ++mi)
                    #pragma unroll
                    for (int r = 0; r < 4; ++r) {
                        const int gr = row0 + wr * 64 + mi * 16 + kcl * 4 + r;
                        o[(size_t)gr * 576 + n] = acc[mi][ni][r] + bv;
                    }
            }
        } else {
            float* o = (float*)outp;
            const float bv = bias1[n];
            #pragma unroll
            for (int mi = 0; mi < 4; ++mi)
                #pragma unroll
                for (int r = 0; r < 4; ++r) {
                    const int gr = row0 + wr * 64 + mi * 16 + kcl * 4 + r;
                    o[(size_t)gr * 256 + n] = acc[mi][ni][r] + bv;
                }
        }
    }
}

// ---------------------------------------------------------------------------
// Sampling v2: wave = (b,q,h). Phase 1: lane j (<24) computes sample j's 4
// clamped element-offsets + 4 attn-premultiplied corner weights (validity
// baked into weights); softmax = 32-lane shuffle reduce, ONE exp per lane.
// Phase 2: 12 iters, half k = sample 2i+k: shfl-broadcast plan, 4 coalesced
// bf16 gathers (d = lane&31), 4 FMA. Output written in gemm-tiled order.
// ---------------------------------------------------------------------------
__global__ __launch_bounds__(256, 8) void sample_kernel(
    const ushort* __restrict__ value,   // [B][NH][S][HD] bf16
    const float*  __restrict__ projQ,   // [8192][576] : [0:384)=off, [384:576)=logits
    const float*  __restrict__ refp,    // [B][NQ][2]
    ushort* __restrict__ out_preB)      // tiled [64][8][4][2][64][8]
{
    const int wib  = threadIdx.x >> 6;
    const int lane = threadIdx.x & 63;
    const int half = lane >> 5, dl = lane & 31;
    const int j = lane & 31;            // halves replicate phase 1
    const int jc = min(j, 23);

    const int bid = blockIdx.x;
    const int swz = (bid & 7) * 2048 + (bid >> 3);   // bijective XCD swizzle
    const int bh = swz >> 9;
    const int q  = ((swz & 511) << 2) + wib;
    const int b  = bh >> 3, h = bh & 7;
    const int row = b * NQ + q;
    const float* rowQ = projQ + (size_t)row * 576;

    // ---- phase 1 ----
    const float2 offj = *(const float2*)(rowQ + h * 48 + jc * 2);
    const float lg = rowQ[384 + h * 24 + jc];
    const float refx = refp[(size_t)row * 2 + 0];
    const float refy = refp[(size_t)row * 2 + 1];

    const int   wi = j < 8 ? 100 : (j < 16 ? 50 : 25);   // square levels
    const int   st = j < 8 ? 0   : (j < 16 ? 10000 : 12500);
    const float wf = (float)wi;

    const float x = fmaf(refx, wf, offj.x) - 0.5f;
    const float y = fmaf(refy, wf, offj.y) - 0.5f;
    const float x0f = floorf(x), y0f = floorf(y);
    const float fx = x - x0f, fy = y - y0f;
    const int ix = (int)x0f, iy = (int)y0f;

    const float cx0 = (ix >= 0 && ix < wi)         ? (1.f - fx) : 0.f;
    const float cx1 = (ix + 1 >= 0 && ix + 1 < wi) ? fx         : 0.f;
    const float cy0 = (iy >= 0 && iy < wi)         ? (1.f - fy) : 0.f;
    const float cy1 = (iy + 1 >= 0 && iy + 1 < wi) ? fy         : 0.f;
    const int xc0 = min(max(ix, 0), wi - 1),  xc1 = min(max(ix + 1, 0), wi - 1);
    const int yc0 = min(max(iy, 0), wi - 1),  yc1 = min(max(iy + 1, 0), wi - 1);

    // softmax across lanes 0..23 (lanes 24..31 neutral)
    float mm = (j < 24) ? lg : -1e30f;
    #pragma unroll
    for (int d = 1; d < 32; d <<= 1) mm = fmaxf(mm, __shfl_xor(mm, d));
    float ex = (j < 24) ? __expf(lg - mm) : 0.f;
    float ssum = ex;
    #pragma unroll
    for (int d = 1; d < 32; d <<= 1) ssum += __shfl_xor(ssum, d);
    const float aw = ex * (1.0f / ssum);

    const float ww00 = aw * cy0 * cx0, ww10 = aw * cy0 * cx1;
    const float ww01 = aw * cy1 * cx0, ww11 = aw * cy1 * cx1;
    const uint o00 = (uint)(st + yc0 * wi + xc0) * 32u;
    const uint o10 = (uint)(st + yc0 * wi + xc1) * 32u;
    const uint o01 = (uint)(st + yc1 * wi + xc0) * 32u;
    const uint o11 = (uint)(st + yc1 * wi + xc1) * 32u;

    // ---- phase 2 ----
    const ushort* slab = value + (size_t)(b * NH_ + h) * (S_ * HD_) + dl;
    float acc = 0.f;
    #pragma unroll
    for (int i = 0; i < 12; ++i) {
        const int src = 2 * i + half;
        const uint a00 = (uint)__shfl((int)o00, src), a10 = (uint)__shfl((int)o10, src);
        const uint a01 = (uint)__shfl((int)o01, src), a11 = (uint)__shfl((int)o11, src);
        const float u00 = __shfl(ww00, src), u10 = __shfl(ww10, src);
        const float u01 = __shfl(ww01, src), u11 = __shfl(ww11, src);
        acc = fmaf(u00, bf2f(slab[a00]), acc);
        acc = fmaf(u10, bf2f(slab[a10]), acc);
        acc = fmaf(u01, bf2f(slab[a01]), acc);
        acc = fmaf(u11, bf2f(slab[a11]), acc);
    }
    acc += __shfl_xor(acc, 32);
    if (half == 0) {
        const uint toff = ((uint)(row >> 7)) * 32768u + (uint)h * 4096u
                        + (uint)(dl >> 3) * 1024u + (uint)((row >> 6) & 1) * 512u
                        + (uint)(row & 63) * 8u + (uint)(dl & 7);
        out_preB[toff] = f2bf(acc);
    }
}

extern "C" void kernel_launch(void* const* d_in, const int* in_sizes, int n_in,
                              void* d_out, int out_size, void* d_ws, size_t ws_size,
                              hipStream_t stream)
{
    const float* query  = (const float*)d_in[0];
    const float* memory = (const float*)d_in[1];
    const float* refp   = (const float*)d_in[2];
    const float* W_off  = (const float*)d_in[3];
    const float* b_off  = (const float*)d_in[4];
    const float* W_attn = (const float*)d_in[5];
    const float* b_attn = (const float*)d_in[6];
    const float* W_val  = (const float*)d_in[7];
    const float* b_val  = (const float*)d_in[8];
    const float* W_out  = (const float*)d_in[9];
    const float* b_out  = (const float*)d_in[10];

    // ws layout (ushort units); memB region reused for projQ+out_preB after
    // gemm<0> consumes it (single-stream ordering).
    ushort* ws       = (ushort*)d_ws;
    ushort* memB     = ws;                        // 13,500,416 (4 x 103 tiles)
    ushort* queryB   = ws + 13500416;             //  2,097,152 (64 tiles)
    ushort* W_valT   = ws + 15597568;             //     65,536 (2 tiles)
    ushort* WcatT    = ws + 15663104;             //    163,840 (5 tiles)
    ushort* W_outT   = ws + 15826944;             //     65,536 (2 tiles)
    ushort* valueB   = ws + 15892480;             // 13,440,000  (total 58.7 MB)
    float*  projQ    = (float*)ws;                //  4,718,592 f32 (aliases memB)
    ushort* out_preB = ws + 9437184;              //  2,097,152 (aliases memB tail)

    hipLaunchKernelGGL(convert_kernel, dim3(7760), dim3(256), 0, stream,
                       memory, query, W_off, W_attn, W_val, W_out,
                       memB, queryB, WcatT, W_valT, W_outT);
    hipLaunchKernelGGL((gemm_mfma<0>), dim3(103, 2, 4), dim3(256), 0, stream,
                       memB, W_valT, b_val, nullptr, (void*)valueB);
    hipLaunchKernelGGL((gemm_mfma<1>), dim3(64, 5, 1), dim3(256), 0, stream,
                       queryB, WcatT, b_off, b_attn, (void*)projQ);
    hipLaunchKernelGGL(sample_kernel, dim3(16384), dim3(256), 0, stream,
                       valueB, projQ, refp, out_preB);
    hipLaunchKernelGGL((gemm_mfma<2>), dim3(64, 2, 1), dim3(256), 0, stream,
                       out_preB, W_outT, b_out, nullptr, (void*)d_out);
}

// Round 13
// 219.849 us; speedup vs baseline: 1.1728x; 1.1728x over previous
//
#include <hip/hip_runtime.h>
#include <math.h>

#define NH_ 8
#define L_ 3
#define P_ 8
#define HD_ 32
#define C_ 256
#define B_ 4
#define NQ 2048
#define S_ 13125

typedef unsigned short ushort;
typedef unsigned int uint;

using short8 = __attribute__((ext_vector_type(8))) short;
using f32x4  = __attribute__((ext_vector_type(4))) float;

typedef unsigned int u32_as1 __attribute__((address_space(1)));
typedef unsigned int u32_as3 __attribute__((address_space(3)));

__device__ __forceinline__ void gload16(const ushort* g, ushort* l) {
    // async global->LDS, 16B per lane; LDS dest = wave-uniform base + lane*16
    __builtin_amdgcn_global_load_lds((const u32_as1*)g, (u32_as3*)l, 16, 0, 0);
}

__device__ __forceinline__ ushort f2bf(float f) {
    union { float f; uint i; } v; v.f = f;
    const uint x = v.i;
    return (ushort)((x + 0x7FFFu + ((x >> 16) & 1u)) >> 16);  // RTNE
}
__device__ __forceinline__ float bf2f(ushort u) {
    union { uint i; float f; } v; v.i = ((uint)u) << 16; return v.f;
}
__device__ __forceinline__ uint pk2(float lo, float hi) {
    return (uint)f2bf(lo) | ((uint)f2bf(hi) << 16);
}

// ---------------------------------------------------------------------------
// Tiled bf16 layout for GEMM staging (per logical [R][256] matrix, R pad 128):
//   ushort offset(r,k) = t*32768 + s*4096 + w*1024 + rh*512 + lane*8 + e
//   where t=r>>7, rh=(r>>6)&1, lane=r&63, s=k>>5, w=(k>>3)&3, e=k&7.
// One chunk id = 8 ushorts; chunk c within tile: s=c>>9, w=(c>>7)&3,
// rh=(c>>6)&1, lane=c&63. Staging then reads 1KB contiguous per wave-inst.
// ---------------------------------------------------------------------------
__global__ __launch_bounds__(256) void convert_kernel(
    const float* __restrict__ memory, const float* __restrict__ query,
    const float* __restrict__ W_off, const float* __restrict__ W_attn,
    const float* __restrict__ W_val, const float* __restrict__ W_out,
    ushort* __restrict__ memB, ushort* __restrict__ queryB,
    ushort* __restrict__ WcatT, ushort* __restrict__ W_valT,
    ushort* __restrict__ W_outT)
{
    const uint id = blockIdx.x * 256u + threadIdx.x;
    float v[8];

    if (id < 1687552u) {                       // memB: [z][103 tiles][4096 chunks]
        const uint z = id / 421888u, rem = id % 421888u;
        const uint t = rem >> 12, c = rem & 4095u;
        const uint s = c >> 9, w = (c >> 7) & 3u, rh = (c >> 6) & 1u, ln = c & 63u;
        const uint r = min(t * 128u + rh * 64u + ln, 13124u);
        const uint k = s * 32u + w * 8u;
        const float* src = memory + ((size_t)z * 13125u + r) * 256u + k;
        const float4 a = *(const float4*)src;
        const float4 b = *(const float4*)(src + 4);
        uint4 o; o.x = pk2(a.x, a.y); o.y = pk2(a.z, a.w);
                 o.z = pk2(b.x, b.y); o.w = pk2(b.z, b.w);
        *(uint4*)(memB + (size_t)id * 8) = o;
    } else if (id < 1949696u) {                // queryB: 64 tiles (8192 rows exact)
        const uint local = id - 1687552u;
        const uint t = local >> 12, c = local & 4095u;
        const uint s = c >> 9, w = (c >> 7) & 3u, rh = (c >> 6) & 1u, ln = c & 63u;
        const uint r = t * 128u + rh * 64u + ln;
        const uint k = s * 32u + w * 8u;
        const float* src = query + (size_t)r * 256u + k;
        const float4 a = *(const float4*)src;
        const float4 b = *(const float4*)(src + 4);
        uint4 o; o.x = pk2(a.x, a.y); o.y = pk2(a.z, a.w);
                 o.z = pk2(b.x, b.y); o.w = pk2(b.z, b.w);
        *(uint4*)(queryB + (size_t)local * 8) = o;
    } else if (id < 1957888u) {                // W_valT: 2 tiles (n=256 exact)
        const uint local = id - 1949696u;
        const uint t = local >> 12, c = local & 4095u;
        const uint s = c >> 9, w = (c >> 7) & 3u, rh = (c >> 6) & 1u, ln = c & 63u;
        const uint n = t * 128u + rh * 64u + ln;
        const uint k = s * 32u + w * 8u;
        #pragma unroll
        for (int e = 0; e < 8; ++e) v[e] = W_val[(size_t)(k + e) * 256u + n];
        uint4 o; o.x = pk2(v[0], v[1]); o.y = pk2(v[2], v[3]);
                 o.z = pk2(v[4], v[5]); o.w = pk2(v[6], v[7]);
        *(uint4*)(W_valT + (size_t)local * 8) = o;
    } else if (id < 1978368u) {                // WcatT: 5 tiles (576 cols, pad clamp)
        const uint local = id - 1957888u;
        const uint t = local >> 12, c = local & 4095u;
        const uint s = c >> 9, w = (c >> 7) & 3u, rh = (c >> 6) & 1u, ln = c & 63u;
        const uint n = min(t * 128u + rh * 64u + ln, 575u);
        const uint k = s * 32u + w * 8u;
        #pragma unroll
        for (int e = 0; e < 8; ++e)
            v[e] = (n < 384u) ? W_off[(size_t)(k + e) * 384u + n]
                              : W_attn[(size_t)(k + e) * 192u + (n - 384u)];
        uint4 o; o.x = pk2(v[0], v[1]); o.y = pk2(v[2], v[3]);
                 o.z = pk2(v[4], v[5]); o.w = pk2(v[6], v[7]);
        *(uint4*)(WcatT + (size_t)local * 8) = o;
    } else if (id < 1986560u) {                // W_outT: 2 tiles
        const uint local = id - 1978368u;
        const uint t = local >> 12, c = local & 4095u;
        const uint s = c >> 9, w = (c >> 7) & 3u, rh = (c >> 6) & 1u, ln = c & 63u;
        const uint n = t * 128u + rh * 64u + ln;
        const uint k = s * 32u + w * 8u;
        #pragma unroll
        for (int e = 0; e < 8; ++e) v[e] = W_out[(size_t)(k + e) * 256u + n];
        uint4 o; o.x = pk2(v[0], v[1]); o.y = pk2(v[2], v[3]);
                 o.z = pk2(v[4], v[5]); o.w = pk2(v[6], v[7]);
        *(uint4*)(W_outT + (size_t)local * 8) = o;
    }
}

// ---------------------------------------------------------------------------
// bf16 MFMA GEMM on tiled operands. 128x128 tile, 4 waves (2x2), K-step 32,
// 2-phase LDS dbuf, global_load_lds reads 1KB contiguous per instruction.
// MODE 0: A=memB(batch z), WT=W_valT -> value bf16 [B][NH][S][HD] (+b_val)
// MODE 1: A=queryB,        WT=WcatT  -> projQ f32 [8192][576]
// MODE 2: A=out_preB_t,    WT=W_outT -> d_out f32 [8192][256] (+b_out)
// ---------------------------------------------------------------------------
template <int MODE>
__global__ __launch_bounds__(256) void gemm_mfma(
    const ushort* __restrict__ A, const ushort* __restrict__ WT,
    const float* __restrict__ bias1, const float* __restrict__ bias2,
    void* __restrict__ outp)
{
    const int tid = threadIdx.x;
    const int wid = tid >> 6, lane = tid & 63;
    const int l15 = lane & 15, kcl = lane >> 4;
    const int wr = wid >> 1, wc = wid & 1;

    const ushort* Ab;
    if constexpr (MODE == 0) Ab = A + (size_t)blockIdx.z * 3375104u;  // 103*32768
    else                     Ab = A;

    const int row0 = blockIdx.x * 128, n0 = blockIdx.y * 128;

    __shared__ ushort As[2][4096];   // [kchunk(=wid)][128 rows][8 k]
    __shared__ ushort Bs[2][4096];

    f32x4 acc[4][4] = {};

    auto stage = [&](int buf, int s) {
        const size_t abase = ((size_t)(blockIdx.x * 8 + s)) * 4096 + wid * 1024 + lane * 8;
        const size_t bbase = ((size_t)(blockIdx.y * 8 + s)) * 4096 + wid * 1024 + lane * 8;
        #pragma unroll
        for (int rh = 0; rh < 2; ++rh) {
            gload16(Ab + abase + rh * 512, &As[buf][wid * 1024 + rh * 512]);
            gload16(WT + bbase + rh * 512, &Bs[buf][wid * 1024 + rh * 512]);
        }
    };

    stage(0, 0);
    __syncthreads();

    #pragma unroll
    for (int kt = 0; kt < 8; ++kt) {
        const int cur = kt & 1;
        if (kt < 7) stage(cur ^ 1, kt + 1);

        short8 af[4], bf[4];
        #pragma unroll
        for (int mi = 0; mi < 4; ++mi)
            af[mi] = *(const short8*)&As[cur][kcl * 1024 + (wr * 64 + mi * 16 + l15) * 8];
        #pragma unroll
        for (int ni = 0; ni < 4; ++ni)
            bf[ni] = *(const short8*)&Bs[cur][kcl * 1024 + (wc * 64 + ni * 16 + l15) * 8];
        #pragma unroll
        for (int mi = 0; mi < 4; ++mi)
            #pragma unroll
            for (int ni = 0; ni < 4; ++ni)
                acc[mi][ni] = __builtin_amdgcn_mfma_f32_16x16x32_bf16(
                    af[mi], bf[ni], acc[mi][ni], 0, 0, 0);
        __syncthreads();
    }

    // epilogue: C/D layout col = lane&15, row = (lane>>4)*4 + reg
    #pragma unroll
    for (int ni = 0; ni < 4; ++ni) {
        const int n = n0 + wc * 64 + ni * 16 + l15;
        if constexpr (MODE == 0) {
            ushort* value = (ushort*)outp;
            const int h = n >> 5, d = n & 31;
            const float bv = bias1[n];
            #pragma unroll
            for (int mi = 0; mi < 4; ++mi)
                #pragma unroll
                for (int r = 0; r < 4; ++r) {
                    const int s = row0 + wr * 64 + mi * 16 + kcl * 4 + r;
                    if (s < S_)
                        value[(((size_t)blockIdx.z * NH_ + h) * S_ + s) * HD_ + d] =
                            f2bf(acc[mi][ni][r] + bv);
                }
        } else if constexpr (MODE == 1) {
            if (n < 576) {
                float* o = (float*)outp;
                const float bv = (n < 384) ? bias1[n] : bias2[n - 384];
                #pragma unroll
                for (int mi = 0; mi < 4; ++mi)
                    #pragma unroll
                    for (int r = 0; r < 4; ++r) {
                        const int gr = row0 + wr * 64 + mi * 16 + kcl * 4 + r;
                        o[(size_t)gr * 576 + n] = acc[mi][ni][r] + bv;
                    }
            }
        } else {
            float* o = (float*)outp;
            const float bv = bias1[n];
            #pragma unroll
            for (int mi = 0; mi < 4; ++mi)
                #pragma unroll
                for (int r = 0; r < 4; ++r) {
                    const int gr = row0 + wr * 64 + mi * 16 + kcl * 4 + r;
                    o[(size_t)gr * 256 + n] = acc[mi][ni][r] + bv;
                }
        }
    }
}

// ---------------------------------------------------------------------------
// Sampling v3: wave = (b,q,h). Phase 1 (lanes 0..23): compute sample j's 4
// clamped BYTE offsets + 4 attn-premultiplied corner weights; write 32B plan
// to LDS (per-wave table, no barrier needed — same-wave dep via lgkmcnt).
// Softmax = 32-lane shuffle reduce, one exp per lane.
// Phase 2: 12 iters; half k = sample 2i+k: 2 broadcast ds_read_b128 fetch the
// plan, 4 gathers via SGPR slab base + 32-bit voffset (1 v_add each), 4 FMA.
// Replaces v2's 96 ds_bpermutes/wave (measured LDS-pipe bound, r9) with 24
// ds_reads. Output written in gemm-tiled order.
// ---------------------------------------------------------------------------
__global__ __launch_bounds__(256, 6) void sample_kernel(
    const ushort* __restrict__ value,   // [B][NH][S][HD] bf16
    const float*  __restrict__ projQ,   // [8192][576] : [0:384)=off, [384:576)=logits
    const float*  __restrict__ refp,    // [B][NQ][2]
    ushort* __restrict__ out_preB)      // tiled [64][8][4][2][64][8]
{
    __shared__ uint plan[4][24][8];     // [wave][sample][o00,o10,o01,o11,w00,w10,w01,w11]

    const int wib  = threadIdx.x >> 6;
    const int lane = threadIdx.x & 63;
    const int half = lane >> 5, dl = lane & 31;
    const int j = lane & 31;            // halves replicate phase-1 math
    const int jc = min(j, 23);

    const int bid = blockIdx.x;
    const int swz = (bid & 7) * 2048 + (bid >> 3);   // bijective XCD swizzle
    const int bh = swz >> 9;
    const int q  = ((swz & 511) << 2) + wib;
    const int b  = bh >> 3, h = bh & 7;
    const int row = b * NQ + q;
    const float* rowQ = projQ + (size_t)row * 576;

    // ---- phase 1 ----
    const float2 offj = *(const float2*)(rowQ + h * 48 + jc * 2);
    const float lg = rowQ[384 + h * 24 + jc];
    const float refx = refp[(size_t)row * 2 + 0];
    const float refy = refp[(size_t)row * 2 + 1];

    const int   wi = j < 8 ? 100 : (j < 16 ? 50 : 25);   // square levels
    const int   st = j < 8 ? 0   : (j < 16 ? 10000 : 12500);
    const float wf = (float)wi;

    const float x = fmaf(refx, wf, offj.x) - 0.5f;
    const float y = fmaf(refy, wf, offj.y) - 0.5f;
    const float x0f = floorf(x), y0f = floorf(y);
    const float fx = x - x0f, fy = y - y0f;
    const int ix = (int)x0f, iy = (int)y0f;

    const float cx0 = (ix >= 0 && ix < wi)         ? (1.f - fx) : 0.f;
    const float cx1 = (ix + 1 >= 0 && ix + 1 < wi) ? fx         : 0.f;
    const float cy0 = (iy >= 0 && iy < wi)         ? (1.f - fy) : 0.f;
    const float cy1 = (iy + 1 >= 0 && iy + 1 < wi) ? fy         : 0.f;
    const int xc0 = min(max(ix, 0), wi - 1),  xc1 = min(max(ix + 1, 0), wi - 1);
    const int yc0 = min(max(iy, 0), wi - 1),  yc1 = min(max(iy + 1, 0), wi - 1);

    // softmax across lanes 0..23 (lanes 24..31 neutral)
    float mm = (j < 24) ? lg : -1e30f;
    #pragma unroll
    for (int d = 1; d < 32; d <<= 1) mm = fmaxf(mm, __shfl_xor(mm, d));
    float ex = (j < 24) ? __expf(lg - mm) : 0.f;
    float ssum = ex;
    #pragma unroll
    for (int d = 1; d < 32; d <<= 1) ssum += __shfl_xor(ssum, d);
    const float aw = ex * (1.0f / ssum);

    if (lane < 24) {                    // one writer per sample (half 0 only)
        plan[wib][lane][0] = (uint)(st + yc0 * wi + xc0) * 64u;   // byte offsets
        plan[wib][lane][1] = (uint)(st + yc0 * wi + xc1) * 64u;
        plan[wib][lane][2] = (uint)(st + yc1 * wi + xc0) * 64u;
        plan[wib][lane][3] = (uint)(st + yc1 * wi + xc1) * 64u;
        plan[wib][lane][4] = __float_as_uint(aw * cy0 * cx0);
        plan[wib][lane][5] = __float_as_uint(aw * cy0 * cx1);
        plan[wib][lane][6] = __float_as_uint(aw * cy1 * cx0);
        plan[wib][lane][7] = __float_as_uint(aw * cy1 * cx1);
    }

    // ---- phase 2 ----
    // wave-uniform slab base pinned to SGPR; per-lane d contributes a 32-bit
    // byte voffset only -> global_load_ushort v, voff, s[base].
    const uint slabElem = __builtin_amdgcn_readfirstlane(
        (uint)(b * NH_ + h) * (uint)(S_ * HD_));
    const char* slab = (const char*)(value + slabElem);
    const uint dlb = (uint)dl * 2u;

    float acc = 0.f;
    #pragma unroll
    for (int i = 0; i < 12; ++i) {
        const int sidx = 2 * i + half;
        const uint4 po = *(const uint4*)&plan[wib][sidx][0];   // ds_read_b128 (bcast)
        const uint4 pw = *(const uint4*)&plan[wib][sidx][4];   // ds_read_b128 (bcast)
        const float v00 = bf2f(*(const ushort*)(slab + (po.x + dlb)));
        const float v10 = bf2f(*(const ushort*)(slab + (po.y + dlb)));
        const float v01 = bf2f(*(const ushort*)(slab + (po.z + dlb)));
        const float v11 = bf2f(*(const ushort*)(slab + (po.w + dlb)));
        acc = fmaf(__uint_as_float(pw.x), v00, acc);
        acc = fmaf(__uint_as_float(pw.y), v10, acc);
        acc = fmaf(__uint_as_float(pw.z), v01, acc);
        acc = fmaf(__uint_as_float(pw.w), v11, acc);
    }
    acc += __shfl_xor(acc, 32);
    if (half == 0) {
        const uint toff = ((uint)(row >> 7)) * 32768u + (uint)h * 4096u
                        + (uint)(dl >> 3) * 1024u + (uint)((row >> 6) & 1) * 512u
                        + (uint)(row & 63) * 8u + (uint)(dl & 7);
        out_preB[toff] = f2bf(acc);
    }
}

extern "C" void kernel_launch(void* const* d_in, const int* in_sizes, int n_in,
                              void* d_out, int out_size, void* d_ws, size_t ws_size,
                              hipStream_t stream)
{
    const float* query  = (const float*)d_in[0];
    const float* memory = (const float*)d_in[1];
    const float* refp   = (const float*)d_in[2];
    const float* W_off  = (const float*)d_in[3];
    const float* b_off  = (const float*)d_in[4];
    const float* W_attn = (const float*)d_in[5];
    const float* b_attn = (const float*)d_in[6];
    const float* W_val  = (const float*)d_in[7];
    const float* b_val  = (const float*)d_in[8];
    const float* W_out  = (const float*)d_in[9];
    const float* b_out  = (const float*)d_in[10];

    // ws layout (ushort units); memB region reused for projQ+out_preB after
    // gemm<0> consumes it (single-stream ordering).
    ushort* ws       = (ushort*)d_ws;
    ushort* memB     = ws;                        // 13,500,416 (4 x 103 tiles)
    ushort* queryB   = ws + 13500416;             //  2,097,152 (64 tiles)
    ushort* W_valT   = ws + 15597568;             //     65,536 (2 tiles)
    ushort* WcatT    = ws + 15663104;             //    163,840 (5 tiles)
    ushort* W_outT   = ws + 15826944;             //     65,536 (2 tiles)
    ushort* valueB   = ws + 15892480;             // 13,440,000  (total 58.7 MB)
    float*  projQ    = (float*)ws;                //  4,718,592 f32 (aliases memB)
    ushort* out_preB = ws + 9437184;              //  2,097,152 (aliases memB tail)

    hipLaunchKernelGGL(convert_kernel, dim3(7760), dim3(256), 0, stream,
                       memory, query, W_off, W_attn, W_val, W_out,
                       memB, queryB, WcatT, W_valT, W_outT);
    hipLaunchKernelGGL((gemm_mfma<0>), dim3(103, 2, 4), dim3(256), 0, stream,
                       memB, W_valT, b_val, nullptr, (void*)valueB);
    hipLaunchKernelGGL((gemm_mfma<1>), dim3(64, 5, 1), dim3(256), 0, stream,
                       queryB, WcatT, b_off, b_attn, (void*)projQ);
    hipLaunchKernelGGL(sample_kernel, dim3(16384), dim3(256), 0, stream,
                       valueB, projQ, refp, out_preB);
    hipLaunchKernelGGL((gemm_mfma<2>), dim3(64, 2, 1), dim3(256), 0, stream,
                       out_preB, W_outT, b_out, nullptr, (void*)d_out);
}